// Round 2
// baseline (321.848 us; speedup 1.0000x reference)
//
#include <hip/hip_runtime.h>
#include <hip/hip_bf16.h>

#define B_ 64
#define T_ 2048
#define D_ 512     // K dim of GEMM (KD=QD)
#define A_ 512     // attention dim (N of GEMM)
#define BM 128     // t-rows per block
#define BK 32      // K step
#define NSTEP (D_/BK)

typedef float f32x4_t __attribute__((ext_vector_type(4)));
typedef short bf16x8_t __attribute__((ext_vector_type(8)));

__device__ __forceinline__ bf16x8_t pack8(float4 v0, float4 v1) {
  union { __hip_bfloat162 h[4]; bf16x8_t v; } r;
  r.h[0] = __float22bfloat162_rn(make_float2(v0.x, v0.y));
  r.h[1] = __float22bfloat162_rn(make_float2(v0.z, v0.w));
  r.h[2] = __float22bfloat162_rn(make_float2(v1.x, v1.y));
  r.h[3] = __float22bfloat162_rn(make_float2(v1.z, v1.w));
  return r.v;
}

// ---------------- prep: q = query @ Wq + bq (fp32, exact) ----------------
__global__ void __launch_bounds__(256) qproj_kernel(
    const float* __restrict__ query, const float* __restrict__ Wq,
    const float* __restrict__ bq, float* __restrict__ qbuf) {
  __shared__ float qs[D_];
  const int b = blockIdx.x, tid = threadIdx.x;
  qs[tid] = query[b*D_ + tid];
  qs[tid+256] = query[b*D_ + tid + 256];
  __syncthreads();
  float a0 = bq[tid], a1 = bq[tid+256];
  for (int d = 0; d < D_; ++d) {
    const float qv = qs[d];
    a0 += qv * Wq[d*A_ + tid];
    a1 += qv * Wq[d*A_ + tid + 256];
  }
  qbuf[b*A_ + tid] = a0;
  qbuf[b*A_ + tid+256] = a1;
}

// ---- prep: Wk [D][A] fp32 -> bf16 slab; row (ks,a) = 32 k-values of col a ----
// lane fragment read (col a, k-octet lq) = slab + ((ks*512 + a)*64 + lq*16) bytes.
__global__ void __launch_bounds__(256) wkprep_kernel(
    const float* __restrict__ Wk, unsigned int* __restrict__ slab) {
  __shared__ float tile[32][65];
  const int kb = blockIdx.x >> 3;
  const int a0 = (blockIdx.x & 7) * 64;
  const int tid = threadIdx.x;
  for (int p = 0; p < 8; ++p) {
    const int idx = p*256 + tid;
    const int k = idx >> 6, al = idx & 63;
    tile[k][al] = Wk[(kb*32 + k)*A_ + a0 + al];
  }
  __syncthreads();
  const int al = tid >> 2, c = tid & 3;
  const int a = a0 + al;
  union { __hip_bfloat162 h[2]; uint2 u; } w0, w1;
  w0.h[0] = __float22bfloat162_rn(make_float2(tile[c*8+0][al], tile[c*8+1][al]));
  w0.h[1] = __float22bfloat162_rn(make_float2(tile[c*8+2][al], tile[c*8+3][al]));
  w1.h[0] = __float22bfloat162_rn(make_float2(tile[c*8+4][al], tile[c*8+5][al]));
  w1.h[1] = __float22bfloat162_rn(make_float2(tile[c*8+6][al], tile[c*8+7][al]));
  uint4 w = make_uint4(w0.u.x, w0.u.y, w1.u.x, w1.u.y);
  *(uint4*)(slab + (kb*512 + a)*16 + c*4) = w;
}

// ------- fused energy: e[b,t] = sum_a Wo[a]*tanh(q[b,a] + (keys@Wk)[b,t,a] + cover[b,t]*Wc[a]) -------
// No LDS in the K-loop, no barriers: A and B fragments load straight from
// global (A = keys fp32->bf16 in-register; B = L2-resident prepped slab).
__global__ void __launch_bounds__(512, 2) energy_kernel(
    const float* __restrict__ keys, const float* __restrict__ cover,
    const int* __restrict__ key_len, const unsigned char* __restrict__ slab,
    const float* __restrict__ qbuf, const float* __restrict__ Wc,
    const float* __restrict__ Wo, float* __restrict__ energy) {
  __shared__ float redbuf[8][64];

  const int b = blockIdx.y;
  const int t0 = blockIdx.x * BM;
  const int kl = key_len[b];
  if (t0 >= kl) return;   // fully-masked tile: energies never read downstream

  const int tid = threadIdx.x;
  const int wid = tid >> 6;
  const int lane = tid & 63;
  const int lq = lane >> 4, lr = lane & 15;
  const int wm = wid >> 2, wn = wid & 3;   // wave tile: rows wm*64..+64, cols wn*128..+128

  const float* akeys = keys + ((size_t)b * T_ + t0 + wm*64 + lr) * D_ + lq*8;
  const unsigned char* bslab = slab + (size_t)(wn*128 + lr)*64 + lq*16;

  f32x4_t acc[4][8];
  #pragma unroll
  for (int i = 0; i < 4; ++i)
    #pragma unroll
    for (int j = 0; j < 8; ++j) acc[i][j] = 0.0f;

  #pragma unroll 2
  for (int ks = 0; ks < NSTEP; ++ks) {
    bf16x8_t aF[4], bF[8];
    #pragma unroll
    for (int mf = 0; mf < 4; ++mf) {
      const float* p = akeys + mf*16*D_ + ks*BK;
      aF[mf] = pack8(*(const float4*)p, *(const float4*)(p + 4));
    }
    #pragma unroll
    for (int nf = 0; nf < 8; ++nf)
      bF[nf] = *(const bf16x8_t*)(bslab + (size_t)ks*32768 + nf*1024);
    #pragma unroll
    for (int mf = 0; mf < 4; ++mf)
      #pragma unroll
      for (int nf = 0; nf < 8; ++nf)
        acc[mf][nf] = __builtin_amdgcn_mfma_f32_16x16x32_bf16(aF[mf], bF[nf], acc[mf][nf], 0, 0, 0);
  }

  // epilogue: pre = acc + q[n] + cover[t]*Wc[n]; ep += Wo[n]*tanh(pre)
  float cov[4][4];
  #pragma unroll
  for (int mf = 0; mf < 4; ++mf)
    #pragma unroll
    for (int j = 0; j < 4; ++j)
      cov[mf][j] = cover[(size_t)b*T_ + t0 + wm*64 + mf*16 + lq*4 + j];

  float ep[4][4];
  #pragma unroll
  for (int mf = 0; mf < 4; ++mf)
    #pragma unroll
    for (int j = 0; j < 4; ++j) ep[mf][j] = 0.f;

  #pragma unroll
  for (int nf = 0; nf < 8; ++nf) {
    const int n = wn*128 + nf*16 + lr;
    const float qv = qbuf[b*A_ + n];
    const float wc = Wc[n];
    const float wo = Wo[n];
    #pragma unroll
    for (int mf = 0; mf < 4; ++mf)
      #pragma unroll
      for (int j = 0; j < 4; ++j) {
        float p = acc[mf][nf][j] + qv + cov[mf][j] * wc;
        p = fminf(fmaxf(p, -15.f), 15.f);
        const float t2 = __expf(2.f * p);
        ep[mf][j] += wo * ((t2 - 1.f) / (t2 + 1.f));
      }
  }
  #pragma unroll
  for (int mf = 0; mf < 4; ++mf)
    #pragma unroll
    for (int j = 0; j < 4; ++j) {
      float v = ep[mf][j];
      v += __shfl_xor(v, 1); v += __shfl_xor(v, 2);
      v += __shfl_xor(v, 4); v += __shfl_xor(v, 8);
      ep[mf][j] = v;
    }
  if (lr == 0) {
    #pragma unroll
    for (int mf = 0; mf < 4; ++mf)
      #pragma unroll
      for (int j = 0; j < 4; ++j)
        redbuf[wid][mf*16 + lq*4 + j] = ep[mf][j];
  }
  __syncthreads();
  if (tid < BM) {
    const int wmm = tid >> 6, rl = tid & 63;
    const float e = redbuf[wmm*4+0][rl] + redbuf[wmm*4+1][rl]
                  + redbuf[wmm*4+2][rl] + redbuf[wmm*4+3][rl];
    energy[b*T_ + t0 + tid] = e;
  }
}

// ---------------- masked softmax over T ----------------
__global__ void __launch_bounds__(1024) softmax_kernel(
    const float* __restrict__ energy, const int* __restrict__ key_len,
    float* __restrict__ attn) {
  __shared__ float sredM[16];
  __shared__ float sredS[16];
  const int b = blockIdx.x, tid = threadIdx.x;
  const int kl = key_len[b];
  const float e0 = (tid < kl) ? energy[b*T_ + tid] : -3.0e38f;
  const float e1 = (tid + 1024 < kl) ? energy[b*T_ + tid + 1024] : -3.0e38f;
  float m = fmaxf(e0, e1);
  for (int s = 32; s; s >>= 1) m = fmaxf(m, __shfl_xor(m, s));
  if ((tid & 63) == 0) sredM[tid >> 6] = m;
  __syncthreads();
  float M = -3.0e38f;
  #pragma unroll
  for (int i = 0; i < 16; ++i) M = fmaxf(M, sredM[i]);
  const float p0 = (tid < kl) ? __expf(e0 - M) : 0.f;
  const float p1 = (tid + 1024 < kl) ? __expf(e1 - M) : 0.f;
  float s = p0 + p1;
  for (int k = 32; k; k >>= 1) s += __shfl_xor(s, k);
  if ((tid & 63) == 0) sredS[tid >> 6] = s;
  __syncthreads();
  float S = 0.f;
  #pragma unroll
  for (int i = 0; i < 16; ++i) S += sredS[i];
  const float inv = 1.f / S;
  attn[b*T_ + tid] = p0 * inv;
  attn[b*T_ + tid + 1024] = p1 * inv;
}

// ---------------- context: partial sums over t-chunks, then combine ----------------
__global__ void __launch_bounds__(256) ctxpart_kernel(
    const float* __restrict__ value, const float* __restrict__ attn,
    const int* __restrict__ key_len, float* __restrict__ partial) {
  __shared__ float att_s[256];
  const int b = blockIdx.y, ch = blockIdx.x;
  const int tid = threadIdx.x;
  const int kl = key_len[b];
  const int tstart = ch * 256;
  const int tend = min(256, kl - tstart);
  float ax = 0.f, ay = 0.f;
  if (tend > 0) {
    att_s[tid] = attn[b*T_ + tstart + tid];
    __syncthreads();
    const float2* vp = (const float2*)(value + ((size_t)b*T_ + tstart)*D_) + tid;
    #pragma unroll 4
    for (int i = 0; i < tend; ++i) {
      const float w = att_s[i];
      const float2 v = vp[(size_t)i * 256];
      ax += w * v.x; ay += w * v.y;
    }
  }
  float2* pp = (float2*)(partial + (size_t)(b*8 + ch)*D_) + tid;
  *pp = make_float2(ax, ay);
}

__global__ void __launch_bounds__(256) ctxsum_kernel(
    const float* __restrict__ partial, float* __restrict__ ctx) {
  const int b = blockIdx.x, tid = threadIdx.x;
  float sx = 0.f, sy = 0.f;
  #pragma unroll
  for (int c = 0; c < 8; ++c) {
    const float2 v = *((const float2*)(partial + (size_t)(b*8 + c)*D_) + tid);
    sx += v.x; sy += v.y;
  }
  *((float2*)(ctx + (size_t)b*D_) + tid) = make_float2(sx, sy);
}

extern "C" void kernel_launch(void* const* d_in, const int* in_sizes, int n_in,
                              void* d_out, int out_size, void* d_ws, size_t ws_size,
                              hipStream_t stream) {
  const float* query  = (const float*)d_in[0];
  const float* keys   = (const float*)d_in[1];
  const float* value  = (const float*)d_in[2];
  const float* cover  = (const float*)d_in[3];
  const int*   key_len= (const int*)d_in[4];
  const float* Wq     = (const float*)d_in[5];
  const float* bq     = (const float*)d_in[6];
  const float* Wk     = (const float*)d_in[7];
  const float* Wc     = (const float*)d_in[8];
  const float* Wo     = (const float*)d_in[9];

  float* out = (float*)d_out;
  float* ctx_out  = out;            // [64,512]
  float* attn_out = out + B_*A_;    // [64,1,2048]

  float* ws = (float*)d_ws;
  float* qbuf    = ws;                           // 32768 f32
  float* energy  = ws + 32768;                   // 131072 f32
  float* partial = ws + 32768 + 131072;          // 262144 f32
  unsigned int* slab = (unsigned int*)(ws + 32768 + 131072 + 262144);  // 512 KB

  qproj_kernel<<<B_, 256, 0, stream>>>(query, Wq, bq, qbuf);
  wkprep_kernel<<<128, 256, 0, stream>>>(Wk, slab);
  energy_kernel<<<dim3(T_/BM, B_), 512, 0, stream>>>(
      keys, cover, key_len, (const unsigned char*)slab, qbuf, Wc, Wo, energy);
  softmax_kernel<<<B_, 1024, 0, stream>>>(energy, key_len, attn_out);
  ctxpart_kernel<<<dim3(8, B_), 256, 0, stream>>>(value, attn_out, key_len, partial);
  ctxsum_kernel<<<B_, 256, 0, stream>>>(partial, ctx_out);
}

// Round 3
// 224.550 us; speedup vs baseline: 1.4333x; 1.4333x over previous
//
#include <hip/hip_runtime.h>
#include <hip/hip_bf16.h>

#define B_ 64
#define T_ 2048
#define D_ 512     // K dim of GEMM (KD=QD)
#define A_ 512     // attention dim (N of GEMM)
#define BM 128     // t-rows per block
#define BN 128     // a-cols per block (A split into 4 col-blocks)
#define BK 32      // K step
#define NSTEP (D_/BK)

typedef float f32x4_t __attribute__((ext_vector_type(4)));
typedef short bf16x8_t __attribute__((ext_vector_type(8)));

#define GLL16(g, l) __builtin_amdgcn_global_load_lds( \
    (const __attribute__((address_space(1))) void*)(g), \
    (__attribute__((address_space(3))) void*)(l), 16, 0, 0)

__device__ __forceinline__ uint2 pack8u(float4 v0, float4 v1) {
  union { __hip_bfloat162 h[2]; uint2 u; } r;
  r.h[0] = __float22bfloat162_rn(make_float2(v0.x, v0.y));
  r.h[1] = __float22bfloat162_rn(make_float2(v0.z, v0.w));
  uint2 lo = r.u;
  r.h[0] = __float22bfloat162_rn(make_float2(v1.x, v1.y));
  r.h[1] = __float22bfloat162_rn(make_float2(v1.z, v1.w));
  return make_uint2(lo.x, lo.y), r.u;  // (unused comma removed below)
}

// ---------------- prep: q = query @ Wq + bq (fp32, exact) ----------------
__global__ void __launch_bounds__(256) qproj_kernel(
    const float* __restrict__ query, const float* __restrict__ Wq,
    const float* __restrict__ bq, float* __restrict__ qbuf) {
  __shared__ float qs[D_];
  const int b = blockIdx.x, tid = threadIdx.x;
  qs[tid] = query[b*D_ + tid];
  qs[tid+256] = query[b*D_ + tid + 256];
  __syncthreads();
  float a0 = bq[tid], a1 = bq[tid+256];
  for (int d = 0; d < D_; ++d) {
    const float qv = qs[d];
    a0 += qv * Wq[d*A_ + tid];
    a1 += qv * Wq[d*A_ + tid + 256];
  }
  qbuf[b*A_ + tid] = a0;
  qbuf[b*A_ + tid+256] = a1;
}

// ---- prep: Wk [D][A] fp32 -> bf16 slab [kb][a][chunk-swizzled 64B rows] ----
// slab row a of k-block kb holds k = kb*32 + c*8 .. +8 at chunk slot c ^ ((a>>1)&3).
__global__ void __launch_bounds__(256) wkprep_kernel(
    const float* __restrict__ Wk, unsigned int* __restrict__ slab) {
  __shared__ float tile[32][65];
  const int kb = blockIdx.x >> 3;
  const int a0 = (blockIdx.x & 7) * 64;
  const int tid = threadIdx.x;
  for (int p = 0; p < 8; ++p) {
    const int idx = p*256 + tid;
    const int k = idx >> 6, al = idx & 63;
    tile[k][al] = Wk[(kb*32 + k)*A_ + a0 + al];
  }
  __syncthreads();
  const int al = tid >> 2, c = tid & 3;
  const int a = a0 + al;
  union { __hip_bfloat162 h[2]; uint2 u; } w0, w1;
  w0.h[0] = __float22bfloat162_rn(make_float2(tile[c*8+0][al], tile[c*8+1][al]));
  w0.h[1] = __float22bfloat162_rn(make_float2(tile[c*8+2][al], tile[c*8+3][al]));
  w1.h[0] = __float22bfloat162_rn(make_float2(tile[c*8+4][al], tile[c*8+5][al]));
  w1.h[1] = __float22bfloat162_rn(make_float2(tile[c*8+6][al], tile[c*8+7][al]));
  const int cpos = c ^ ((a >> 1) & 3);
  *(uint4*)(slab + (kb*512 + a)*16 + cpos*4) =
      make_uint4(w0.u.x, w0.u.y, w1.u.x, w1.u.y);
}

// ------- fused energy (partial over 128 cols): m97-geometry 128x128 tile -------
__global__ void __launch_bounds__(256, 4) energy_kernel(
    const float* __restrict__ keys, const float* __restrict__ cover,
    const int* __restrict__ key_len, const unsigned char* __restrict__ slab,
    const float* __restrict__ qbuf, const float* __restrict__ Wc,
    const float* __restrict__ Wo, float* __restrict__ epart) {
  __shared__ __align__(16) unsigned char Abuf[2][BM*64];   // 2 x 8 KB
  __shared__ __align__(16) unsigned char Bbuf[2][BN*64];   // 2 x 8 KB
  __shared__ float redbuf[4][64];

  // XCD-chunk swizzle: dispatch d -> XCD d%8; give each XCD a contiguous
  // logical run so the 4 col-blocks of one keys-panel share an XCD's L2.
  const int d = blockIdx.x;                  // 0..4095
  const int logical = (d & 7) * 512 + (d >> 3);
  const int ct = logical & 3;                // col-block: cols ct*128..+128
  const int tt = (logical >> 2) & 15;        // t-tile
  const int b  = logical >> 6;

  const int t0 = tt * BM;
  const int kl = key_len[b];
  if (t0 >= kl) return;   // fully-masked tile: energies never read downstream

  const int tid = threadIdx.x;
  const int wid = tid >> 6;
  const int lane = tid & 63;
  const int lq = lane >> 4, lr = lane & 15;
  const int wm = wid >> 1, wn = wid & 1;     // 2x2 waves, 64x64 each

  // A staging role: row = tid>>1 (0..127), half = tid&1 (16 fp32 each)
  const int arow = tid >> 1, ahalf = tid & 1;
  const float* aptr = keys + ((size_t)b * T_ + t0 + arow) * D_ + ahalf * 16;
  const int as = (arow >> 1) & 3;
  const int ad0 = arow*64 + (((ahalf*2+0) ^ as) << 4);
  const int ad1 = arow*64 + (((ahalf*2+1) ^ as) << 4);

  const unsigned char* bsl = slab + ct * 8192 + wid * 1024 + lane * 16;

  f32x4_t acc[4][4];
  #pragma unroll
  for (int i = 0; i < 4; ++i)
    #pragma unroll
    for (int j = 0; j < 4; ++j) acc[i][j] = 0.0f;

  int a_off[4], b_off[4];
  #pragma unroll
  for (int mf = 0; mf < 4; ++mf) {
    const int r = wm*64 + mf*16 + lr;
    a_off[mf] = r*64 + ((lq ^ ((r >> 1) & 3)) << 4);
  }
  #pragma unroll
  for (int nf = 0; nf < 4; ++nf) {
    const int r = wn*64 + nf*16 + lr;
    b_off[nf] = r*64 + ((lq ^ ((r >> 1) & 3)) << 4);
  }

  // prologue: stage ks=0 into buf 0
  {
    const float4 v0 = *(const float4*)(aptr);
    const float4 v1 = *(const float4*)(aptr + 4);
    const float4 v2 = *(const float4*)(aptr + 8);
    const float4 v3 = *(const float4*)(aptr + 12);
    union { __hip_bfloat162 h[2]; uint2 u; } p0, p1, p2, p3;
    p0.h[0] = __float22bfloat162_rn(make_float2(v0.x, v0.y));
    p0.h[1] = __float22bfloat162_rn(make_float2(v0.z, v0.w));
    p1.h[0] = __float22bfloat162_rn(make_float2(v1.x, v1.y));
    p1.h[1] = __float22bfloat162_rn(make_float2(v1.z, v1.w));
    p2.h[0] = __float22bfloat162_rn(make_float2(v2.x, v2.y));
    p2.h[1] = __float22bfloat162_rn(make_float2(v2.z, v2.w));
    p3.h[0] = __float22bfloat162_rn(make_float2(v3.x, v3.y));
    p3.h[1] = __float22bfloat162_rn(make_float2(v3.z, v3.w));
    *(uint4*)(&Abuf[0][ad0]) = make_uint4(p0.u.x, p0.u.y, p1.u.x, p1.u.y);
    *(uint4*)(&Abuf[0][ad1]) = make_uint4(p2.u.x, p2.u.y, p3.u.x, p3.u.y);
    GLL16(bsl,        &Bbuf[0][wid*1024]);
    GLL16(bsl + 4096, &Bbuf[0][4096 + wid*1024]);
  }
  __syncthreads();

  for (int ks = 0; ks < NSTEP; ++ks) {
    const int cur = ks & 1;
    const bool pre = (ks + 1 < NSTEP);
    float4 v0, v1, v2, v3;
    if (pre) {  // T14: issue next-tile loads early (hide under MFMA)
      const float* p = aptr + (ks + 1) * BK;
      v0 = *(const float4*)(p);
      v1 = *(const float4*)(p + 4);
      v2 = *(const float4*)(p + 8);
      v3 = *(const float4*)(p + 12);
      const unsigned char* g = bsl + (size_t)(ks+1)*32768;
      GLL16(g,        &Bbuf[cur^1][wid*1024]);
      GLL16(g + 4096, &Bbuf[cur^1][4096 + wid*1024]);
    }
    bf16x8_t aF[4], bF[4];
    #pragma unroll
    for (int mf = 0; mf < 4; ++mf) aF[mf] = *(const bf16x8_t*)(&Abuf[cur][a_off[mf]]);
    #pragma unroll
    for (int nf = 0; nf < 4; ++nf) bF[nf] = *(const bf16x8_t*)(&Bbuf[cur][b_off[nf]]);
    #pragma unroll
    for (int mf = 0; mf < 4; ++mf)
      #pragma unroll
      for (int nf = 0; nf < 4; ++nf)
        acc[mf][nf] = __builtin_amdgcn_mfma_f32_16x16x32_bf16(aF[mf], bF[nf], acc[mf][nf], 0, 0, 0);
    if (pre) {  // write-late half of A staging
      union { __hip_bfloat162 h[2]; uint2 u; } p0, p1, p2, p3;
      p0.h[0] = __float22bfloat162_rn(make_float2(v0.x, v0.y));
      p0.h[1] = __float22bfloat162_rn(make_float2(v0.z, v0.w));
      p1.h[0] = __float22bfloat162_rn(make_float2(v1.x, v1.y));
      p1.h[1] = __float22bfloat162_rn(make_float2(v1.z, v1.w));
      p2.h[0] = __float22bfloat162_rn(make_float2(v2.x, v2.y));
      p2.h[1] = __float22bfloat162_rn(make_float2(v2.z, v2.w));
      p3.h[0] = __float22bfloat162_rn(make_float2(v3.x, v3.y));
      p3.h[1] = __float22bfloat162_rn(make_float2(v3.z, v3.w));
      *(uint4*)(&Abuf[cur^1][ad0]) = make_uint4(p0.u.x, p0.u.y, p1.u.x, p1.u.y);
      *(uint4*)(&Abuf[cur^1][ad1]) = make_uint4(p2.u.x, p2.u.y, p3.u.x, p3.u.y);
    }
    __syncthreads();
  }

  // epilogue: pre = acc + q[n] + cover[t]*Wc[n]; ep += Wo[n]*tanh(pre)
  float cov[4][4];
  #pragma unroll
  for (int mf = 0; mf < 4; ++mf)
    #pragma unroll
    for (int j = 0; j < 4; ++j)
      cov[mf][j] = cover[(size_t)b*T_ + t0 + wm*64 + mf*16 + lq*4 + j];

  float ep[4][4];
  #pragma unroll
  for (int mf = 0; mf < 4; ++mf)
    #pragma unroll
    for (int j = 0; j < 4; ++j) ep[mf][j] = 0.f;

  #pragma unroll
  for (int nf = 0; nf < 4; ++nf) {
    const int n = ct*BN + wn*64 + nf*16 + lr;
    const float qv = qbuf[b*A_ + n];
    const float wc = Wc[n];
    const float wo = Wo[n];
    #pragma unroll
    for (int mf = 0; mf < 4; ++mf)
      #pragma unroll
      for (int j = 0; j < 4; ++j) {
        float p = acc[mf][nf][j] + qv + cov[mf][j] * wc;
        p = fminf(fmaxf(p, -15.f), 15.f);
        const float t2 = __expf(2.f * p);
        ep[mf][j] += wo * ((t2 - 1.f) * __builtin_amdgcn_rcpf(t2 + 1.f));
      }
  }
  #pragma unroll
  for (int mf = 0; mf < 4; ++mf)
    #pragma unroll
    for (int j = 0; j < 4; ++j) {
      float v = ep[mf][j];
      v += __shfl_xor(v, 1); v += __shfl_xor(v, 2);
      v += __shfl_xor(v, 4); v += __shfl_xor(v, 8);
      ep[mf][j] = v;
    }
  if (lr == 0) {
    #pragma unroll
    for (int mf = 0; mf < 4; ++mf)
      #pragma unroll
      for (int j = 0; j < 4; ++j)
        redbuf[wid][mf*16 + lq*4 + j] = ep[mf][j];
  }
  __syncthreads();
  if (tid < BM) {
    const int wmm = tid >> 6, rl = tid & 63;
    epart[((size_t)ct*B_ + b)*T_ + t0 + tid] = redbuf[wmm*2][rl] + redbuf[wmm*2+1][rl];
  }
}

// ---------------- masked softmax over T (sums 4 col-partials) ----------------
__global__ void __launch_bounds__(1024) softmax_kernel(
    const float* __restrict__ epart, const int* __restrict__ key_len,
    float* __restrict__ attn) {
  __shared__ float sredM[16];
  __shared__ float sredS[16];
  const int b = blockIdx.x, tid = threadIdx.x;
  const int kl = key_len[b];
  float e0 = -3.0e38f, e1 = -3.0e38f;
  if (tid < kl)
    e0 = epart[(size_t)b*T_ + tid] + epart[((size_t)B_ + b)*T_ + tid]
       + epart[((size_t)2*B_ + b)*T_ + tid] + epart[((size_t)3*B_ + b)*T_ + tid];
  if (tid + 1024 < kl)
    e1 = epart[(size_t)b*T_ + tid+1024] + epart[((size_t)B_ + b)*T_ + tid+1024]
       + epart[((size_t)2*B_ + b)*T_ + tid+1024] + epart[((size_t)3*B_ + b)*T_ + tid+1024];
  float m = fmaxf(e0, e1);
  for (int s = 32; s; s >>= 1) m = fmaxf(m, __shfl_xor(m, s));
  if ((tid & 63) == 0) sredM[tid >> 6] = m;
  __syncthreads();
  float M = -3.0e38f;
  #pragma unroll
  for (int i = 0; i < 16; ++i) M = fmaxf(M, sredM[i]);
  const float p0 = (tid < kl) ? __expf(e0 - M) : 0.f;
  const float p1 = (tid + 1024 < kl) ? __expf(e1 - M) : 0.f;
  float s = p0 + p1;
  for (int k = 32; k; k >>= 1) s += __shfl_xor(s, k);
  if ((tid & 63) == 0) sredS[tid >> 6] = s;
  __syncthreads();
  float S = 0.f;
  #pragma unroll
  for (int i = 0; i < 16; ++i) S += sredS[i];
  const float inv = 1.f / S;
  attn[b*T_ + tid] = p0 * inv;
  attn[b*T_ + tid + 1024] = p1 * inv;
}

// ---------------- context: partial sums over t-chunks, then combine ----------------
__global__ void __launch_bounds__(256) ctxpart_kernel(
    const float* __restrict__ value, const float* __restrict__ attn,
    const int* __restrict__ key_len, float* __restrict__ partial) {
  __shared__ float att_s[256];
  const int b = blockIdx.y, ch = blockIdx.x;
  const int tid = threadIdx.x;
  const int kl = key_len[b];
  const int tstart = ch * 256;
  const int tend = min(256, kl - tstart);
  float ax = 0.f, ay = 0.f;
  if (tend > 0) {
    att_s[tid] = attn[b*T_ + tstart + tid];
    __syncthreads();
    const float2* vp = (const float2*)(value + ((size_t)b*T_ + tstart)*D_) + tid;
    #pragma unroll 4
    for (int i = 0; i < tend; ++i) {
      const float w = att_s[i];
      const float2 v = vp[(size_t)i * 256];
      ax += w * v.x; ay += w * v.y;
    }
  }
  float2* pp = (float2*)(partial + (size_t)(b*8 + ch)*D_) + tid;
  *pp = make_float2(ax, ay);
}

__global__ void __launch_bounds__(256) ctxsum_kernel(
    const float* __restrict__ partial, float* __restrict__ ctx) {
  const int b = blockIdx.x, tid = threadIdx.x;
  float sx = 0.f, sy = 0.f;
  #pragma unroll
  for (int c = 0; c < 8; ++c) {
    const float2 v = *((const float2*)(partial + (size_t)(b*8 + c)*D_) + tid);
    sx += v.x; sy += v.y;
  }
  *((float2*)(ctx + (size_t)b*D_) + tid) = make_float2(sx, sy);
}

extern "C" void kernel_launch(void* const* d_in, const int* in_sizes, int n_in,
                              void* d_out, int out_size, void* d_ws, size_t ws_size,
                              hipStream_t stream) {
  const float* query  = (const float*)d_in[0];
  const float* keys   = (const float*)d_in[1];
  const float* value  = (const float*)d_in[2];
  const float* cover  = (const float*)d_in[3];
  const int*   key_len= (const int*)d_in[4];
  const float* Wq     = (const float*)d_in[5];
  const float* bq     = (const float*)d_in[6];
  const float* Wk     = (const float*)d_in[7];
  const float* Wc     = (const float*)d_in[8];
  const float* Wo     = (const float*)d_in[9];

  float* out = (float*)d_out;
  float* ctx_out  = out;            // [64,512]
  float* attn_out = out + B_*A_;    // [64,1,2048]

  float* ws = (float*)d_ws;
  float* qbuf    = ws;                                   // 32768 f32
  float* epart   = ws + 32768;                           // 4*131072 f32
  float* partial = ws + 32768 + 524288;                  // 262144 f32
  unsigned int* slab = (unsigned int*)(ws + 32768 + 524288 + 262144);  // 512 KB

  qproj_kernel<<<B_, 256, 0, stream>>>(query, Wq, bq, qbuf);
  wkprep_kernel<<<128, 256, 0, stream>>>(Wk, slab);
  energy_kernel<<<B_*(T_/BM)*(A_/BN), 256, 0, stream>>>(
      keys, cover, key_len, (const unsigned char*)slab, qbuf, Wc, Wo, epart);
  softmax_kernel<<<B_, 1024, 0, stream>>>(epart, key_len, attn_out);
  ctxpart_kernel<<<dim3(8, B_), 256, 0, stream>>>(value, attn_out, key_len, partial);
  ctxsum_kernel<<<B_, 256, 0, stream>>>(partial, ctx_out);
}